// Round 7
// baseline (304.438 us; speedup 1.0000x reference)
//
#include <hip/hip_runtime.h>
#include <hip/hip_cooperative_groups.h>
#include <math.h>

namespace cg = cooperative_groups;

#define D 1024
#define NROWS 16384
#define NBUF 512
#define NBLK 512     // fused grid: 4 waves/block, 8 rows/wave; 2 blocks/CU co-resident
#define NSLOT 512    // fallback path only

// ws layout (float indices)
#define OFF_MEAN 0      // 1024 floats: column sums of y1 (device atomicAdd)
#define OFF_KEY  1024   // unsigned long long at byte 4096
#define OFF_GATE 2048   // fallback only
#define OFF_PART 20480  // fallback only
#define ZERO_BYTES 4112 // MEAN + KEY

typedef float nfloat4 __attribute__((ext_vector_type(4)));

__device__ __forceinline__ float4 ld4(const float* p) { return *(const float4*)p; }
__device__ __forceinline__ void st4_nt(float* p, float4 v) {
    nfloat4 nv = { v.x, v.y, v.z, v.w };
    __builtin_nontemporal_store(nv, (nfloat4*)p);
}

__device__ __forceinline__ float wave_red(float v) {
    #pragma unroll
    for (int off = 32; off > 0; off >>= 1) v += __shfl_xor(v, off, 64);
    return v;
}

__device__ __forceinline__ float gelu_f(float x) {
    float x2 = x * x;
    float t1 = fmaf(0.044715f, x2, 1.0f);
    float u2 = (1.5957691216057308f * x) * t1;
    float e  = __expf(u2);
    float r  = __builtin_amdgcn_rcpf(e + 1.0f);
    return fmaf(-x, r, x);
}

__device__ __forceinline__ float4 gelu4(float4 x) {
    float4 y;
    y.x = gelu_f(x.x); y.y = gelu_f(x.y); y.z = gelu_f(x.z); y.w = gelu_f(x.w);
    return y;
}

// Load one row pair (rr, rr+1) into explicit register sets XA/XB.
#define LOADPAIR(rr, XA, XB) do {                                              \
    const float* _pA = x + (size_t)(rr) * D;                                   \
    const float* _pB = _pA + D;                                                \
    _Pragma("unroll")                                                          \
    for (int _j = 0; _j < 4; ++_j) {                                           \
        XA[_j] = ld4(&_pA[col[_j]]);                                           \
        XB[_j] = ld4(&_pB[col[_j]]);                                           \
    }                                                                          \
} while (0)

// =================== FUSED cooperative kernel ================================
// 512 blocks x 256 threads, 8 rows/wave. y1 (gated gelu output) lives in
// REGISTERS (8 rows x 16 el/lane = 128 VGPR) across two grid syncs:
//   phase1: gates + y1 + column sums -> device atomicAdd into MEAN
//   sync; phase2 (blocks<128): sims + argmax key; sync
//   phase3: decode winner, project y1 (regs) onto v, write out.
// Eliminates 2nd x read, gelu recompute, GATE/PART traffic, 3 kernel drains.
// __launch_bounds__(256,2): VGPR cap 256 -> 2 blocks/CU -> 512 co-resident.
__global__ __launch_bounds__(256, 2) void k_fused(
    const float* __restrict__ x,
    const float* __restrict__ ema_x,  const float* __restrict__ ema_x2,
    const float* __restrict__ ema_y,  const float* __restrict__ ema_y2,
    const float* __restrict__ lti,    const float* __restrict__ lto,
    const float* __restrict__ lai,    const float* __restrict__ lao,
    const float* __restrict__ lkb,    const float* __restrict__ lkd,
    const float* __restrict__ buf,    const float* __restrict__ facil,
    const unsigned char* __restrict__ mask,
    float* __restrict__ ws,           float* __restrict__ out)
{
    cg::grid_group grid = cg::this_grid();
    __shared__ float s_stat[4096];   // ax | mx*ax | ay | my*ay
    __shared__ float s_acc[D];       // phase1: col partials; phase3: reused as v
    __shared__ float s_red[4];
    __shared__ float s_sc[3];
    __shared__ float s_inv;
    const int tid = threadIdx.x, wave = tid >> 6, lane = tid & 63;

    // ---- phase 1: gates + y1 (regs) + column sums ----
    for (int i = tid; i < 1024; i += 256) {
        float mx = ema_x[i];
        float vx = fmaxf(ema_x2[i] - mx * mx, 0.0f);
        float ax = 1.0f / (sqrtf(vx) + 1e-5f);
        s_stat[i]        = ax;
        s_stat[1024 + i] = mx * ax;
        float my = ema_y[i];
        float vy = fmaxf(ema_y2[i] - my * my, 0.0f);
        float ay = 1.0f / (sqrtf(vy) + 1e-5f);
        s_stat[2048 + i] = ay;
        s_stat[3072 + i] = my * ay;
        s_acc[i] = 0.0f;
    }
    __syncthreads();

    const float tau_in = __expf(lti[0]), tau_out = __expf(lto[0]);
    const float a_in  = 1.0f / (1.0f + __expf(-lai[0]));
    const float a_out = 1.0f / (1.0f + __expf(-lao[0]));

    int col[4];
    #pragma unroll
    for (int j = 0; j < 4; ++j) col[j] = 4 * lane + 256 * j;

    float4 acc[4];
    #pragma unroll
    for (int j = 0; j < 4; ++j) acc[j] = make_float4(0.f, 0.f, 0.f, 0.f);

// Compute pair: z-stats, gelu into YA/YB (persist), gate folded in, acc += y1.
#define COMPPAIR_F(XA, XB, YA, YB) do {                                        \
    float zinA = 0.f, zinB = 0.f, zoutA = 0.f, zoutB = 0.f;                    \
    _Pragma("unroll")                                                          \
    for (int j = 0; j < 4; ++j) {                                              \
        float4 a  = *(const float4*)&s_stat[col[j]];                           \
        float4 bb = *(const float4*)&s_stat[1024 + col[j]];                    \
        float d;                                                               \
        d = fmaf(XA[j].x, a.x, -bb.x); zinA = fmaf(d, d, zinA);                \
        d = fmaf(XA[j].y, a.y, -bb.y); zinA = fmaf(d, d, zinA);                \
        d = fmaf(XA[j].z, a.z, -bb.z); zinA = fmaf(d, d, zinA);                \
        d = fmaf(XA[j].w, a.w, -bb.w); zinA = fmaf(d, d, zinA);                \
        d = fmaf(XB[j].x, a.x, -bb.x); zinB = fmaf(d, d, zinB);                \
        d = fmaf(XB[j].y, a.y, -bb.y); zinB = fmaf(d, d, zinB);                \
        d = fmaf(XB[j].z, a.z, -bb.z); zinB = fmaf(d, d, zinB);                \
        d = fmaf(XB[j].w, a.w, -bb.w); zinB = fmaf(d, d, zinB);                \
        YA[j] = gelu4(XA[j]);                                                  \
        YB[j] = gelu4(XB[j]);                                                  \
        float4 ay = *(const float4*)&s_stat[2048 + col[j]];                    \
        float4 by = *(const float4*)&s_stat[3072 + col[j]];                    \
        d = fmaf(YA[j].x, ay.x, -by.x); zoutA = fmaf(d, d, zoutA);             \
        d = fmaf(YA[j].y, ay.y, -by.y); zoutA = fmaf(d, d, zoutA);             \
        d = fmaf(YA[j].z, ay.z, -by.z); zoutA = fmaf(d, d, zoutA);             \
        d = fmaf(YA[j].w, ay.w, -by.w); zoutA = fmaf(d, d, zoutA);             \
        d = fmaf(YB[j].x, ay.x, -by.x); zoutB = fmaf(d, d, zoutB);             \
        d = fmaf(YB[j].y, ay.y, -by.y); zoutB = fmaf(d, d, zoutB);             \
        d = fmaf(YB[j].z, ay.z, -by.z); zoutB = fmaf(d, d, zoutB);             \
        d = fmaf(YB[j].w, ay.w, -by.w); zoutB = fmaf(d, d, zoutB);             \
    }                                                                          \
    zinA  = wave_red(zinA)  * (1.0f / D);                                      \
    zinB  = wave_red(zinB)  * (1.0f / D);                                      \
    zoutA = wave_red(zoutA) * (1.0f / D);                                      \
    zoutB = wave_red(zoutB) * (1.0f / D);                                      \
    float gA = ((1.0f - a_in)  + a_in  * __expf(-tau_in  * zinA)) *            \
               ((1.0f - a_out) + a_out * __expf(-tau_out * zoutA));            \
    float gB = ((1.0f - a_in)  + a_in  * __expf(-tau_in  * zinB)) *            \
               ((1.0f - a_out) + a_out * __expf(-tau_out * zoutB));            \
    _Pragma("unroll")                                                          \
    for (int j = 0; j < 4; ++j) {                                              \
        YA[j].x *= gA; YA[j].y *= gA; YA[j].z *= gA; YA[j].w *= gA;            \
        YB[j].x *= gB; YB[j].y *= gB; YB[j].z *= gB; YB[j].w *= gB;            \
        acc[j].x += YA[j].x + YB[j].x;                                         \
        acc[j].y += YA[j].y + YB[j].y;                                         \
        acc[j].z += YA[j].z + YB[j].z;                                         \
        acc[j].w += YA[j].w + YB[j].w;                                         \
    }                                                                          \
} while (0)

    const int r0 = (blockIdx.x * 4 + wave) * 8;   // 8 rows/wave, 4 pairs
    float4 xA0[4], xB0[4], xA1[4], xB1[4];
    float4 y0A[4], y0B[4], y1A[4], y1B[4], y2A[4], y2B[4], y3A[4], y3B[4];

    LOADPAIR(r0 + 0, xA0, xB0);                 // prologue: pairs 0,1 in flight
    LOADPAIR(r0 + 2, xA1, xB1);
    COMPPAIR_F(xA0, xB0, y0A, y0B);
    LOADPAIR(r0 + 4, xA0, xB0);
    COMPPAIR_F(xA1, xB1, y1A, y1B);
    LOADPAIR(r0 + 6, xA1, xB1);
    COMPPAIR_F(xA0, xB0, y2A, y2B);
    COMPPAIR_F(xA1, xB1, y3A, y3B);
#undef COMPPAIR_F

    #pragma unroll
    for (int j = 0; j < 4; ++j) {
        atomicAdd(&s_acc[col[j] + 0], acc[j].x);
        atomicAdd(&s_acc[col[j] + 1], acc[j].y);
        atomicAdd(&s_acc[col[j] + 2], acc[j].z);
        atomicAdd(&s_acc[col[j] + 3], acc[j].w);
    }
    __syncthreads();
    {   // device-scope atomics: coherent across XCDs (512 contenders/address)
        float4 a4 = *(float4*)&s_acc[4 * tid];
        atomicAdd(&ws[OFF_MEAN + 4 * tid + 0], a4.x);
        atomicAdd(&ws[OFF_MEAN + 4 * tid + 1], a4.y);
        atomicAdd(&ws[OFF_MEAN + 4 * tid + 2], a4.z);
        atomicAdd(&ws[OFF_MEAN + 4 * tid + 3], a4.w);
    }

    grid.sync();

    // ---- phase 2: sims + argmax (blocks 0..127; 4 waves -> 512 buf rows) ----
    if (blockIdx.x < NBUF / 4) {
        float4 mv = ld4(&ws[OFF_MEAN + 4 * tid]);
        float ns = mv.x * mv.x + mv.y * mv.y + mv.z * mv.z + mv.w * mv.w;
        ns = wave_red(ns);
        if (lane == 0) s_red[wave] = ns;
        __syncthreads();
        if (tid == 0) {
            float t = s_red[0] + s_red[1] + s_red[2] + s_red[3];
            s_inv = 1.0f / fmaxf(sqrtf(t), 1e-12f);
        }
        __syncthreads();
        const float inv = s_inv;

        float4 mvv[4];
        #pragma unroll
        for (int j = 0; j < 4; ++j) mvv[j] = ld4(&ws[OFF_MEAN + col[j]]);
        const int n = blockIdx.x * 4 + wave;
        const float* br = buf + (size_t)n * D;
        float dot = 0.f, bns = 0.f;
        #pragma unroll
        for (int j = 0; j < 4; ++j) {
            float4 bv = ld4(&br[col[j]]);
            dot = fmaf(bv.x, mvv[j].x, dot); dot = fmaf(bv.y, mvv[j].y, dot);
            dot = fmaf(bv.z, mvv[j].z, dot); dot = fmaf(bv.w, mvv[j].w, dot);
            bns = fmaf(bv.x, bv.x, bns); bns = fmaf(bv.y, bv.y, bns);
            bns = fmaf(bv.z, bv.z, bns); bns = fmaf(bv.w, bv.w, bns);
        }
        dot = wave_red(dot);
        bns = wave_red(bns);
        if (lane == 0) {
            float sim = -1.0f;
            if (mask[n]) sim = (dot * inv) / fmaxf(sqrtf(bns), 1e-12f);
            unsigned int fb = __float_as_uint(sim);
            unsigned int mono = (fb & 0x80000000u) ? ~fb : (fb | 0x80000000u);
            unsigned long long key = ((unsigned long long)mono << 32) | (unsigned int)(~n);
            atomicMax((unsigned long long*)&ws[OFF_KEY], key);
        }
    }

    grid.sync();

    // ---- phase 3: decode winner, project y1 (regs) onto v, write out ----
    const unsigned long long key = *(const unsigned long long*)&ws[OFF_KEY];
    const int idx = (int)(~(unsigned int)(key & 0xFFFFFFFFull));
    const unsigned int mono = (unsigned int)(key >> 32);
    const unsigned int fb = (mono & 0x80000000u) ? (mono ^ 0x80000000u) : ~mono;
    const float sim = __uint_as_float(fb);

    float4 vt = ld4(&buf[(size_t)idx * D + 4 * tid]);
    float bns = 0.f;
    if (!isfinite(vt.x) || !isfinite(vt.y) || !isfinite(vt.z) || !isfinite(vt.w))
        bns = __uint_as_float(0x7FC00000u);   // NaN poison -> valid=0
    bns += vt.x * vt.x + vt.y * vt.y + vt.z * vt.z + vt.w * vt.w;
    bns = wave_red(bns);
    if (lane == 0) s_red[wave] = bns;
    __syncthreads();
    if (tid == 0) {
        float t = s_red[0] + s_red[1] + s_red[2] + s_red[3];
        int valid = (t >= 1e-12f) ? 1 : 0;    // NaN compares false
        float sim_val = fminf(fmaxf(sim, 0.0f), 1.0f);
        float fl = facil[idx] * ((sim_val > 0.88f) ? 2.0f : 1.0f);
        float mod = (fl - 1.0f) * sim_val;
        float kb = fminf(fmaxf(__expf(lkb[0]), 0.01f), 4.0f);
        float kd = fminf(fmaxf(__expf(lkd[0]), 0.01f), 0.9f);
        float boost = 1.0f + kb * mod;
        float damp = fmaxf(0.01f, 1.0f - kd * mod);
        s_sc[0] = valid ? damp : 1.0f;
        s_sc[1] = valid ? (boost - damp) : 0.0f;
        s_sc[2] = (float)valid;
    }
    __syncthreads();
    const float dampe = s_sc[0], coef = s_sc[1];
    if (s_sc[2] == 0.0f) vt = make_float4(0.f, 0.f, 0.f, 0.f);
    *(float4*)&s_acc[4 * tid] = vt;           // s_acc reused as v broadcast
    __syncthreads();

    float4 vv[4];
    #pragma unroll
    for (int j = 0; j < 4; ++j) vv[j] = *(const float4*)&s_acc[col[j]];

#define OUTPAIR(rr, YA, YB) do {                                               \
    float projA = 0.f, projB = 0.f;                                            \
    _Pragma("unroll")                                                          \
    for (int j = 0; j < 4; ++j) {                                              \
        projA = fmaf(YA[j].x, vv[j].x, projA); projA = fmaf(YA[j].y, vv[j].y, projA); \
        projA = fmaf(YA[j].z, vv[j].z, projA); projA = fmaf(YA[j].w, vv[j].w, projA); \
        projB = fmaf(YB[j].x, vv[j].x, projB); projB = fmaf(YB[j].y, vv[j].y, projB); \
        projB = fmaf(YB[j].z, vv[j].z, projB); projB = fmaf(YB[j].w, vv[j].w, projB); \
    }                                                                          \
    projA = wave_red(projA);                                                   \
    projB = wave_red(projB);                                                   \
    const float pcA = projA * coef, pcB = projB * coef;                        \
    float* oA = out + (size_t)(rr) * D;                                        \
    float* oB = oA + D;                                                        \
    _Pragma("unroll")                                                          \
    for (int j = 0; j < 4; ++j) {                                              \
        float4 o;                                                              \
        o.x = fmaf(YA[j].x, dampe, pcA * vv[j].x);                             \
        o.y = fmaf(YA[j].y, dampe, pcA * vv[j].y);                             \
        o.z = fmaf(YA[j].z, dampe, pcA * vv[j].z);                             \
        o.w = fmaf(YA[j].w, dampe, pcA * vv[j].w);                             \
        st4_nt(&oA[col[j]], o);                                                \
        o.x = fmaf(YB[j].x, dampe, pcB * vv[j].x);                             \
        o.y = fmaf(YB[j].y, dampe, pcB * vv[j].y);                             \
        o.z = fmaf(YB[j].z, dampe, pcB * vv[j].z);                             \
        o.w = fmaf(YB[j].w, dampe, pcB * vv[j].w);                             \
        st4_nt(&oB[col[j]], o);                                                \
    }                                                                          \
} while (0)

    OUTPAIR(r0 + 0, y0A, y0B);
    OUTPAIR(r0 + 2, y1A, y1B);
    OUTPAIR(r0 + 4, y2A, y2B);
    OUTPAIR(r0 + 6, y3A, y3B);
#undef OUTPAIR
}

// =================== FALLBACK: r6 4-kernel path ==============================
__global__ __launch_bounds__(256, 2) void k_passA(const float* __restrict__ x,
                                                  const float* __restrict__ ema_x,
                                                  const float* __restrict__ ema_x2,
                                                  const float* __restrict__ ema_y,
                                                  const float* __restrict__ ema_y2,
                                                  const float* __restrict__ lti,
                                                  const float* __restrict__ lto,
                                                  const float* __restrict__ lai,
                                                  const float* __restrict__ lao,
                                                  float* __restrict__ ws) {
    __shared__ float s_stat[4096];
    __shared__ float s_acc[D];
    const int tid = threadIdx.x, wave = tid >> 6, lane = tid & 63;

    for (int i = tid; i < 1024; i += 256) {
        float mx = ema_x[i];
        float vx = fmaxf(ema_x2[i] - mx * mx, 0.0f);
        float ax = 1.0f / (sqrtf(vx) + 1e-5f);
        s_stat[i]        = ax;
        s_stat[1024 + i] = mx * ax;
        float my = ema_y[i];
        float vy = fmaxf(ema_y2[i] - my * my, 0.0f);
        float ay = 1.0f / (sqrtf(vy) + 1e-5f);
        s_stat[2048 + i] = ay;
        s_stat[3072 + i] = my * ay;
        s_acc[i] = 0.0f;
    }
    __syncthreads();

    const float tau_in = __expf(lti[0]), tau_out = __expf(lto[0]);
    const float a_in  = 1.0f / (1.0f + __expf(-lai[0]));
    const float a_out = 1.0f / (1.0f + __expf(-lao[0]));

    int col[4];
    #pragma unroll
    for (int j = 0; j < 4; ++j) col[j] = 4 * lane + 256 * j;

    float4 acc[4];
    #pragma unroll
    for (int j = 0; j < 4; ++j) acc[j] = make_float4(0.f, 0.f, 0.f, 0.f);

#define COMPPAIR_A(rr, XA, XB) do {                                            \
    float4 yA[4], yB[4];                                                       \
    float zinA = 0.f, zinB = 0.f, zoutA = 0.f, zoutB = 0.f;                    \
    _Pragma("unroll")                                                          \
    for (int j = 0; j < 4; ++j) {                                              \
        float4 a  = *(const float4*)&s_stat[col[j]];                           \
        float4 bb = *(const float4*)&s_stat[1024 + col[j]];                    \
        float d;                                                               \
        d = fmaf(XA[j].x, a.x, -bb.x); zinA = fmaf(d, d, zinA);                \
        d = fmaf(XA[j].y, a.y, -bb.y); zinA = fmaf(d, d, zinA);                \
        d = fmaf(XA[j].z, a.z, -bb.z); zinA = fmaf(d, d, zinA);                \
        d = fmaf(XA[j].w, a.w, -bb.w); zinA = fmaf(d, d, zinA);                \
        d = fmaf(XB[j].x, a.x, -bb.x); zinB = fmaf(d, d, zinB);                \
        d = fmaf(XB[j].y, a.y, -bb.y); zinB = fmaf(d, d, zinB);                \
        d = fmaf(XB[j].z, a.z, -bb.z); zinB = fmaf(d, d, zinB);                \
        d = fmaf(XB[j].w, a.w, -bb.w); zinB = fmaf(d, d, zinB);                \
        yA[j] = gelu4(XA[j]);                                                  \
        yB[j] = gelu4(XB[j]);                                                  \
        float4 ay = *(const float4*)&s_stat[2048 + col[j]];                    \
        float4 by = *(const float4*)&s_stat[3072 + col[j]];                    \
        d = fmaf(yA[j].x, ay.x, -by.x); zoutA = fmaf(d, d, zoutA);             \
        d = fmaf(yA[j].y, ay.y, -by.y); zoutA = fmaf(d, d, zoutA);             \
        d = fmaf(yA[j].z, ay.z, -by.z); zoutA = fmaf(d, d, zoutA);             \
        d = fmaf(yA[j].w, ay.w, -by.w); zoutA = fmaf(d, d, zoutA);             \
        d = fmaf(yB[j].x, ay.x, -by.x); zoutB = fmaf(d, d, zoutB);             \
        d = fmaf(yB[j].y, ay.y, -by.y); zoutB = fmaf(d, d, zoutB);             \
        d = fmaf(yB[j].z, ay.z, -by.z); zoutB = fmaf(d, d, zoutB);             \
        d = fmaf(yB[j].w, ay.w, -by.w); zoutB = fmaf(d, d, zoutB);             \
    }                                                                          \
    zinA  = wave_red(zinA)  * (1.0f / D);                                      \
    zinB  = wave_red(zinB)  * (1.0f / D);                                      \
    zoutA = wave_red(zoutA) * (1.0f / D);                                      \
    zoutB = wave_red(zoutB) * (1.0f / D);                                      \
    float gA = ((1.0f - a_in)  + a_in  * __expf(-tau_in  * zinA)) *            \
               ((1.0f - a_out) + a_out * __expf(-tau_out * zoutA));            \
    float gB = ((1.0f - a_in)  + a_in  * __expf(-tau_in  * zinB)) *            \
               ((1.0f - a_out) + a_out * __expf(-tau_out * zoutB));            \
    if (lane == 0) { ws[OFF_GATE + (rr)] = gA; ws[OFF_GATE + (rr) + 1] = gB; } \
    _Pragma("unroll")                                                          \
    for (int j = 0; j < 4; ++j) {                                              \
        acc[j].x = fmaf(yA[j].x, gA, fmaf(yB[j].x, gB, acc[j].x));             \
        acc[j].y = fmaf(yA[j].y, gA, fmaf(yB[j].y, gB, acc[j].y));             \
        acc[j].z = fmaf(yA[j].z, gA, fmaf(yB[j].z, gB, acc[j].z));             \
        acc[j].w = fmaf(yA[j].w, gA, fmaf(yB[j].w, gB, acc[j].w));             \
    }                                                                          \
} while (0)

    const int r0 = (blockIdx.x * 4 + wave) * 8;
    float4 xA0[4], xB0[4], xA1[4], xB1[4];

    LOADPAIR(r0 + 0, xA0, xB0);
    LOADPAIR(r0 + 2, xA1, xB1);
    COMPPAIR_A(r0 + 0, xA0, xB0);
    LOADPAIR(r0 + 4, xA0, xB0);
    COMPPAIR_A(r0 + 2, xA1, xB1);
    LOADPAIR(r0 + 6, xA1, xB1);
    COMPPAIR_A(r0 + 4, xA0, xB0);
    COMPPAIR_A(r0 + 6, xA1, xB1);
#undef COMPPAIR_A

    #pragma unroll
    for (int j = 0; j < 4; ++j) {
        atomicAdd(&s_acc[col[j] + 0], acc[j].x);
        atomicAdd(&s_acc[col[j] + 1], acc[j].y);
        atomicAdd(&s_acc[col[j] + 2], acc[j].z);
        atomicAdd(&s_acc[col[j] + 3], acc[j].w);
    }
    __syncthreads();
    *(float4*)&ws[OFF_PART + (size_t)blockIdx.x * D + 4 * tid] = *(float4*)&s_acc[4 * tid];
}

__global__ __launch_bounds__(256) void k_mean(float* __restrict__ ws) {
    const int tid = threadIdx.x;
    const float* P = &ws[OFF_PART + (size_t)blockIdx.x * 16 * D];
    float4 s = make_float4(0.f, 0.f, 0.f, 0.f);
    #pragma unroll
    for (int i = 0; i < 16; ++i) {
        float4 v = ld4(&P[(size_t)i * D + 4 * tid]);
        s.x += v.x; s.y += v.y; s.z += v.z; s.w += v.w;
    }
    atomicAdd(&ws[OFF_MEAN + 4 * tid + 0], s.x);
    atomicAdd(&ws[OFF_MEAN + 4 * tid + 1], s.y);
    atomicAdd(&ws[OFF_MEAN + 4 * tid + 2], s.z);
    atomicAdd(&ws[OFF_MEAN + 4 * tid + 3], s.w);
}

__global__ __launch_bounds__(256) void k_sims(const float* __restrict__ buf,
                                              const unsigned char* __restrict__ mask,
                                              float* __restrict__ ws) {
    __shared__ float s_red[4];
    __shared__ float s_inv;
    const int tid = threadIdx.x, wave = tid >> 6, lane = tid & 63;

    float4 mv = ld4(&ws[OFF_MEAN + 4 * tid]);
    float ns = mv.x * mv.x + mv.y * mv.y + mv.z * mv.z + mv.w * mv.w;
    ns = wave_red(ns);
    if (lane == 0) s_red[wave] = ns;
    __syncthreads();
    if (tid == 0) {
        float t = s_red[0] + s_red[1] + s_red[2] + s_red[3];
        s_inv = 1.0f / fmaxf(sqrtf(t), 1e-12f);
    }
    __syncthreads();
    const float inv = s_inv;

    int col[4];
    float4 mvv[4];
    #pragma unroll
    for (int j = 0; j < 4; ++j) {
        col[j] = 4 * lane + 256 * j;
        mvv[j] = ld4(&ws[OFF_MEAN + col[j]]);
    }
    const int n = blockIdx.x * 4 + wave;
    const float* br = buf + (size_t)n * D;
    float dot = 0.f, bns = 0.f;
    #pragma unroll
    for (int j = 0; j < 4; ++j) {
        float4 bv = ld4(&br[col[j]]);
        dot = fmaf(bv.x, mvv[j].x, dot); dot = fmaf(bv.y, mvv[j].y, dot);
        dot = fmaf(bv.z, mvv[j].z, dot); dot = fmaf(bv.w, mvv[j].w, dot);
        bns = fmaf(bv.x, bv.x, bns); bns = fmaf(bv.y, bv.y, bns);
        bns = fmaf(bv.z, bv.z, bns); bns = fmaf(bv.w, bv.w, bns);
    }
    dot = wave_red(dot);
    bns = wave_red(bns);
    if (lane == 0) {
        float sim = -1.0f;
        if (mask[n]) sim = (dot * inv) / fmaxf(sqrtf(bns), 1e-12f);
        unsigned int fb = __float_as_uint(sim);
        unsigned int mono = (fb & 0x80000000u) ? ~fb : (fb | 0x80000000u);
        unsigned long long key = ((unsigned long long)mono << 32) | (unsigned int)(~n);
        atomicMax((unsigned long long*)&ws[OFF_KEY], key);
    }
}

__global__ __launch_bounds__(256, 2) void k_passB(const float* __restrict__ x,
                                                  const float* __restrict__ buf,
                                                  const float* __restrict__ facil,
                                                  const float* __restrict__ lkb,
                                                  const float* __restrict__ lkd,
                                                  const float* __restrict__ ws,
                                                  float* __restrict__ out) {
    __shared__ float s_v[D];
    __shared__ float s_red[4];
    __shared__ float s_sc[3];
    const int tid = threadIdx.x, wave = tid >> 6, lane = tid & 63;

    const unsigned long long key = *(const unsigned long long*)&ws[OFF_KEY];
    const int idx = (int)(~(unsigned int)(key & 0xFFFFFFFFull));
    const unsigned int mono = (unsigned int)(key >> 32);
    const unsigned int fb = (mono & 0x80000000u) ? (mono ^ 0x80000000u) : ~mono;
    const float sim = __uint_as_float(fb);

    float4 vt = ld4(&buf[(size_t)idx * D + 4 * tid]);
    float bns = 0.f;
    if (!isfinite(vt.x) || !isfinite(vt.y) || !isfinite(vt.z) || !isfinite(vt.w))
        bns = __uint_as_float(0x7FC00000u);
    bns += vt.x * vt.x + vt.y * vt.y + vt.z * vt.z + vt.w * vt.w;
    bns = wave_red(bns);
    if (lane == 0) s_red[wave] = bns;
    __syncthreads();
    if (tid == 0) {
        float t = s_red[0] + s_red[1] + s_red[2] + s_red[3];
        int valid = (t >= 1e-12f) ? 1 : 0;
        float sim_val = fminf(fmaxf(sim, 0.0f), 1.0f);
        float fl = facil[idx] * ((sim_val > 0.88f) ? 2.0f : 1.0f);
        float mod = (fl - 1.0f) * sim_val;
        float kb = fminf(fmaxf(__expf(lkb[0]), 0.01f), 4.0f);
        float kd = fminf(fmaxf(__expf(lkd[0]), 0.01f), 0.9f);
        float boost = 1.0f + kb * mod;
        float damp = fmaxf(0.01f, 1.0f - kd * mod);
        s_sc[0] = valid ? damp : 1.0f;
        s_sc[1] = valid ? (boost - damp) : 0.0f;
        s_sc[2] = (float)valid;
    }
    __syncthreads();
    const float dampe = s_sc[0], coef = s_sc[1];
    if (s_sc[2] == 0.0f) vt = make_float4(0.f, 0.f, 0.f, 0.f);
    *(float4*)&s_v[4 * tid] = vt;
    __syncthreads();

    int col[4];
    float4 vv[4];
    #pragma unroll
    for (int j = 0; j < 4; ++j) {
        col[j] = 4 * lane + 256 * j;
        vv[j] = *(const float4*)&s_v[col[j]];
    }

#define COMPPAIR_B(rr, XA, XB) do {                                            \
    const float gA = ws[OFF_GATE + (rr)], gB = ws[OFF_GATE + (rr) + 1];        \
    float4 yA[4], yB[4];                                                       \
    float projA = 0.f, projB = 0.f;                                            \
    _Pragma("unroll")                                                          \
    for (int j = 0; j < 4; ++j) {                                              \
        yA[j] = gelu4(XA[j]);                                                  \
        yA[j].x *= gA; yA[j].y *= gA; yA[j].z *= gA; yA[j].w *= gA;            \
        yB[j] = gelu4(XB[j]);                                                  \
        yB[j].x *= gB; yB[j].y *= gB; yB[j].z *= gB; yB[j].w *= gB;            \
        projA = fmaf(yA[j].x, vv[j].x, projA); projA = fmaf(yA[j].y, vv[j].y, projA); \
        projA = fmaf(yA[j].z, vv[j].z, projA); projA = fmaf(yA[j].w, vv[j].w, projA); \
        projB = fmaf(yB[j].x, vv[j].x, projB); projB = fmaf(yB[j].y, vv[j].y, projB); \
        projB = fmaf(yB[j].z, vv[j].z, projB); projB = fmaf(yB[j].w, vv[j].w, projB); \
    }                                                                          \
    projA = wave_red(projA);                                                   \
    projB = wave_red(projB);                                                   \
    const float pcA = projA * coef, pcB = projB * coef;                        \
    float* oA = out + (size_t)(rr) * D;                                        \
    float* oB = oA + D;                                                        \
    _Pragma("unroll")                                                          \
    for (int j = 0; j < 4; ++j) {                                              \
        float4 o;                                                              \
        o.x = fmaf(yA[j].x, dampe, pcA * vv[j].x);                             \
        o.y = fmaf(yA[j].y, dampe, pcA * vv[j].y);                             \
        o.z = fmaf(yA[j].z, dampe, pcA * vv[j].z);                             \
        o.w = fmaf(yA[j].w, dampe, pcA * vv[j].w);                             \
        st4_nt(&oA[col[j]], o);                                                \
        o.x = fmaf(yB[j].x, dampe, pcB * vv[j].x);                             \
        o.y = fmaf(yB[j].y, dampe, pcB * vv[j].y);                             \
        o.z = fmaf(yB[j].z, dampe, pcB * vv[j].z);                             \
        o.w = fmaf(yB[j].w, dampe, pcB * vv[j].w);                             \
        st4_nt(&oB[col[j]], o);                                                \
    }                                                                          \
} while (0)

    const int r0 = (blockIdx.x * 4 + wave) * 8;
    float4 xA0[4], xB0[4], xA1[4], xB1[4];

    LOADPAIR(r0 + 0, xA0, xB0);
    LOADPAIR(r0 + 2, xA1, xB1);
    COMPPAIR_B(r0 + 0, xA0, xB0);
    LOADPAIR(r0 + 4, xA0, xB0);
    COMPPAIR_B(r0 + 2, xA1, xB1);
    LOADPAIR(r0 + 6, xA1, xB1);
    COMPPAIR_B(r0 + 4, xA0, xB0);
    COMPPAIR_B(r0 + 6, xA1, xB1);
#undef COMPPAIR_B
}

extern "C" void kernel_launch(void* const* d_in, const int* in_sizes, int n_in,
                              void* d_out, int out_size, void* d_ws, size_t ws_size,
                              hipStream_t stream) {
    const float* x      = (const float*)d_in[0];
    const float* lti    = (const float*)d_in[1];
    const float* lto    = (const float*)d_in[2];
    const float* lai    = (const float*)d_in[3];
    const float* lao    = (const float*)d_in[4];
    const float* lkb    = (const float*)d_in[5];
    const float* lkd    = (const float*)d_in[6];
    const float* ema_x  = (const float*)d_in[7];
    const float* ema_x2 = (const float*)d_in[8];
    const float* ema_y  = (const float*)d_in[9];
    const float* ema_y2 = (const float*)d_in[10];
    const float* buf    = (const float*)d_in[11];
    const float* facil  = (const float*)d_in[12];
    const unsigned char* mask = (const unsigned char*)d_in[13];
    float* ws  = (float*)d_ws;
    float* out = (float*)d_out;

    (void)hipMemsetAsync(d_ws, 0, ZERO_BYTES, stream);

    void* args[] = { (void*)&x, (void*)&ema_x, (void*)&ema_x2, (void*)&ema_y,
                     (void*)&ema_y2, (void*)&lti, (void*)&lto, (void*)&lai,
                     (void*)&lao, (void*)&lkb, (void*)&lkd, (void*)&buf,
                     (void*)&facil, (void*)&mask, (void*)&ws, (void*)&out };
    hipError_t ce = hipLaunchCooperativeKernel((const void*)k_fused,
                                               dim3(NBLK), dim3(256),
                                               args, 0, stream);
    if (ce != hipSuccess) {
        // fallback: proven r6 4-kernel path
        hipLaunchKernelGGL(k_passA, dim3(NBLK), dim3(256), 0, stream,
                           x, ema_x, ema_x2, ema_y, ema_y2, lti, lto, lai, lao, ws);
        hipLaunchKernelGGL(k_mean,  dim3(NSLOT / 16), dim3(256), 0, stream, ws);
        hipLaunchKernelGGL(k_sims,  dim3(128), dim3(256), 0, stream, buf, mask, ws);
        hipLaunchKernelGGL(k_passB, dim3(NBLK), dim3(256), 0, stream,
                           x, buf, facil, lkb, lkd, ws, out);
    }
}

// Round 8
// 177.082 us; speedup vs baseline: 1.7192x; 1.7192x over previous
//
#include <hip/hip_runtime.h>
#include <math.h>

#define D 1024
#define NROWS 16384
#define NBUF 512
#define NBLKA 512    // passA/passB: 4 waves/block, 8 rows/wave, 4-deep load burst
#define NSLOT 512    // one PART slot per block -> plain stores, no atomics

// ws layout (float indices)
#define OFF_MEAN 0      // 1024 floats: column sums of y1
#define OFF_KEY  1024   // unsigned long long at byte 4096
#define OFF_GATE 2048   // 16384 floats
#define OFF_PART 20480  // NSLOT x 1024 floats (plain-stored partials)
#define ZERO_BYTES 4112 // MEAN + KEY only (PART fully overwritten)

typedef float nfloat4 __attribute__((ext_vector_type(4)));

__device__ __forceinline__ float4 ld4(const float* p) { return *(const float4*)p; }
__device__ __forceinline__ void st4_nt(float* p, float4 v) {
    nfloat4 nv = { v.x, v.y, v.z, v.w };
    __builtin_nontemporal_store(nv, (nfloat4*)p);
}

__device__ __forceinline__ float wave_red(float v) {
    #pragma unroll
    for (int off = 32; off > 0; off >>= 1) v += __shfl_xor(v, off, 64);
    return v;
}

__device__ __forceinline__ float gelu_f(float x) {
    float x2 = x * x;
    float t1 = fmaf(0.044715f, x2, 1.0f);
    float u2 = (1.5957691216057308f * x) * t1;
    float e  = __expf(u2);
    float r  = __builtin_amdgcn_rcpf(e + 1.0f);
    return fmaf(-x, r, x);
}

__device__ __forceinline__ float4 gelu4(float4 x) {
    float4 y;
    y.x = gelu_f(x.x); y.y = gelu_f(x.y); y.z = gelu_f(x.z); y.w = gelu_f(x.w);
    return y;
}

// Load one row pair (rr, rr+1) into explicit register sets XA/XB.
#define LOADPAIR(rr, XA, XB) do {                                              \
    const float* _pA = x + (size_t)(rr) * D;                                   \
    const float* _pB = _pA + D;                                                \
    _Pragma("unroll")                                                          \
    for (int _j = 0; _j < 4; ++_j) {                                           \
        XA[_j] = ld4(&_pA[col[_j]]);                                           \
        XB[_j] = ld4(&_pB[col[_j]]);                                           \
    }                                                                          \
} while (0)

// ---------------- K1: pass A — gates + per-slot column partials ---------------
// 512 blocks x 256; 8 rows/wave. ALL 32 loads (4 pairs, 128 VGPR) issue as one
// dependency-free burst before any compute — fillBuffer's 6.3 TB/s at 8%
// occupancy (r7 datum) proves BW comes from per-wave burst depth, not waves.
// Compiler emits precise vmcnt(24/16/8/0): pair-0 compute starts with 24
// loads still in flight. Explicit named reg sets avoid r1/r2 VGPR collapse.
__global__ __launch_bounds__(256, 2) void k_passA(const float* __restrict__ x,
                                                  const float* __restrict__ ema_x,
                                                  const float* __restrict__ ema_x2,
                                                  const float* __restrict__ ema_y,
                                                  const float* __restrict__ ema_y2,
                                                  const float* __restrict__ lti,
                                                  const float* __restrict__ lto,
                                                  const float* __restrict__ lai,
                                                  const float* __restrict__ lao,
                                                  float* __restrict__ ws) {
    __shared__ float s_stat[4096];   // ax | mx*ax | ay | my*ay
    __shared__ float s_acc[D];
    const int tid = threadIdx.x, wave = tid >> 6, lane = tid & 63;

    for (int i = tid; i < 1024; i += 256) {
        float mx = ema_x[i];
        float vx = fmaxf(ema_x2[i] - mx * mx, 0.0f);
        float ax = 1.0f / (sqrtf(vx) + 1e-5f);
        s_stat[i]        = ax;
        s_stat[1024 + i] = mx * ax;
        float my = ema_y[i];
        float vy = fmaxf(ema_y2[i] - my * my, 0.0f);
        float ay = 1.0f / (sqrtf(vy) + 1e-5f);
        s_stat[2048 + i] = ay;
        s_stat[3072 + i] = my * ay;
        s_acc[i] = 0.0f;
    }
    __syncthreads();

    const float tau_in = __expf(lti[0]), tau_out = __expf(lto[0]);
    const float a_in  = 1.0f / (1.0f + __expf(-lai[0]));
    const float a_out = 1.0f / (1.0f + __expf(-lao[0]));

    int col[4];
    #pragma unroll
    for (int j = 0; j < 4; ++j) col[j] = 4 * lane + 256 * j;

    float4 acc[4];
    #pragma unroll
    for (int j = 0; j < 4; ++j) acc[j] = make_float4(0.f, 0.f, 0.f, 0.f);

#define COMPPAIR_A(rr, XA, XB) do {                                            \
    float4 yA[4], yB[4];                                                       \
    float zinA = 0.f, zinB = 0.f, zoutA = 0.f, zoutB = 0.f;                    \
    _Pragma("unroll")                                                          \
    for (int j = 0; j < 4; ++j) {                                              \
        float4 a  = *(const float4*)&s_stat[col[j]];                           \
        float4 bb = *(const float4*)&s_stat[1024 + col[j]];                    \
        float d;                                                               \
        d = fmaf(XA[j].x, a.x, -bb.x); zinA = fmaf(d, d, zinA);                \
        d = fmaf(XA[j].y, a.y, -bb.y); zinA = fmaf(d, d, zinA);                \
        d = fmaf(XA[j].z, a.z, -bb.z); zinA = fmaf(d, d, zinA);                \
        d = fmaf(XA[j].w, a.w, -bb.w); zinA = fmaf(d, d, zinA);                \
        d = fmaf(XB[j].x, a.x, -bb.x); zinB = fmaf(d, d, zinB);                \
        d = fmaf(XB[j].y, a.y, -bb.y); zinB = fmaf(d, d, zinB);                \
        d = fmaf(XB[j].z, a.z, -bb.z); zinB = fmaf(d, d, zinB);                \
        d = fmaf(XB[j].w, a.w, -bb.w); zinB = fmaf(d, d, zinB);                \
        yA[j] = gelu4(XA[j]);                                                  \
        yB[j] = gelu4(XB[j]);                                                  \
        float4 ay = *(const float4*)&s_stat[2048 + col[j]];                    \
        float4 by = *(const float4*)&s_stat[3072 + col[j]];                    \
        d = fmaf(yA[j].x, ay.x, -by.x); zoutA = fmaf(d, d, zoutA);             \
        d = fmaf(yA[j].y, ay.y, -by.y); zoutA = fmaf(d, d, zoutA);             \
        d = fmaf(yA[j].z, ay.z, -by.z); zoutA = fmaf(d, d, zoutA);             \
        d = fmaf(yA[j].w, ay.w, -by.w); zoutA = fmaf(d, d, zoutA);             \
        d = fmaf(yB[j].x, ay.x, -by.x); zoutB = fmaf(d, d, zoutB);             \
        d = fmaf(yB[j].y, ay.y, -by.y); zoutB = fmaf(d, d, zoutB);             \
        d = fmaf(yB[j].z, ay.z, -by.z); zoutB = fmaf(d, d, zoutB);             \
        d = fmaf(yB[j].w, ay.w, -by.w); zoutB = fmaf(d, d, zoutB);             \
    }                                                                          \
    zinA  = wave_red(zinA)  * (1.0f / D);                                      \
    zinB  = wave_red(zinB)  * (1.0f / D);                                      \
    zoutA = wave_red(zoutA) * (1.0f / D);                                      \
    zoutB = wave_red(zoutB) * (1.0f / D);                                      \
    float gA = ((1.0f - a_in)  + a_in  * __expf(-tau_in  * zinA)) *            \
               ((1.0f - a_out) + a_out * __expf(-tau_out * zoutA));            \
    float gB = ((1.0f - a_in)  + a_in  * __expf(-tau_in  * zinB)) *            \
               ((1.0f - a_out) + a_out * __expf(-tau_out * zoutB));            \
    if (lane == 0) { ws[OFF_GATE + (rr)] = gA; ws[OFF_GATE + (rr) + 1] = gB; } \
    _Pragma("unroll")                                                          \
    for (int j = 0; j < 4; ++j) {                                              \
        acc[j].x = fmaf(yA[j].x, gA, fmaf(yB[j].x, gB, acc[j].x));             \
        acc[j].y = fmaf(yA[j].y, gA, fmaf(yB[j].y, gB, acc[j].y));             \
        acc[j].z = fmaf(yA[j].z, gA, fmaf(yB[j].z, gB, acc[j].z));             \
        acc[j].w = fmaf(yA[j].w, gA, fmaf(yB[j].w, gB, acc[j].w));             \
    }                                                                          \
} while (0)

    const int r0 = (blockIdx.x * 4 + wave) * 8;   // 8 rows/wave, 4 pairs
    float4 xA0[4], xB0[4], xA1[4], xB1[4], xA2[4], xB2[4], xA3[4], xB3[4];

    // full-depth load burst: 32 loads in flight before any compute
    LOADPAIR(r0 + 0, xA0, xB0);
    LOADPAIR(r0 + 2, xA1, xB1);
    LOADPAIR(r0 + 4, xA2, xB2);
    LOADPAIR(r0 + 6, xA3, xB3);
    COMPPAIR_A(r0 + 0, xA0, xB0);
    COMPPAIR_A(r0 + 2, xA1, xB1);
    COMPPAIR_A(r0 + 4, xA2, xB2);
    COMPPAIR_A(r0 + 6, xA3, xB3);
#undef COMPPAIR_A

    #pragma unroll
    for (int j = 0; j < 4; ++j) {
        atomicAdd(&s_acc[col[j] + 0], acc[j].x);
        atomicAdd(&s_acc[col[j] + 1], acc[j].y);
        atomicAdd(&s_acc[col[j] + 2], acc[j].z);
        atomicAdd(&s_acc[col[j] + 3], acc[j].w);
    }
    __syncthreads();
    // unique PART slot per block -> plain store, no atomics, no pre-zero
    *(float4*)&ws[OFF_PART + (size_t)blockIdx.x * D + 4 * tid] = *(float4*)&s_acc[4 * tid];
}

// ---------------- K2: reduce 512 partial slots -> column sums -----------------
__global__ __launch_bounds__(256) void k_mean(float* __restrict__ ws) {
    const int tid = threadIdx.x;
    const float* P = &ws[OFF_PART + (size_t)blockIdx.x * 16 * D];
    float4 s = make_float4(0.f, 0.f, 0.f, 0.f);
    #pragma unroll
    for (int i = 0; i < 16; ++i) {
        float4 v = ld4(&P[(size_t)i * D + 4 * tid]);
        s.x += v.x; s.y += v.y; s.z += v.z; s.w += v.w;
    }
    atomicAdd(&ws[OFF_MEAN + 4 * tid + 0], s.x);
    atomicAdd(&ws[OFF_MEAN + 4 * tid + 1], s.y);
    atomicAdd(&ws[OFF_MEAN + 4 * tid + 2], s.z);
    atomicAdd(&ws[OFF_MEAN + 4 * tid + 3], s.w);
}

// ---------------- K3: sims over buf + argmax via atomicMax key ----------------
__global__ __launch_bounds__(256) void k_sims(const float* __restrict__ buf,
                                              const unsigned char* __restrict__ mask,
                                              float* __restrict__ ws) {
    __shared__ float s_red[4];
    __shared__ float s_inv;
    const int tid = threadIdx.x, wave = tid >> 6, lane = tid & 63;

    float4 mv = ld4(&ws[OFF_MEAN + 4 * tid]);
    float ns = mv.x * mv.x + mv.y * mv.y + mv.z * mv.z + mv.w * mv.w;
    ns = wave_red(ns);
    if (lane == 0) s_red[wave] = ns;
    __syncthreads();
    if (tid == 0) {
        float t = s_red[0] + s_red[1] + s_red[2] + s_red[3];
        s_inv = 1.0f / fmaxf(sqrtf(t), 1e-12f);
    }
    __syncthreads();
    const float inv = s_inv;

    int col[4];
    float4 mvv[4];
    #pragma unroll
    for (int j = 0; j < 4; ++j) {
        col[j] = 4 * lane + 256 * j;
        mvv[j] = ld4(&ws[OFF_MEAN + col[j]]);
    }
    const int n = blockIdx.x * 4 + wave;   // 128 blocks x 4 waves = 512 rows
    const float* br = buf + (size_t)n * D;
    float dot = 0.f, bns = 0.f;
    #pragma unroll
    for (int j = 0; j < 4; ++j) {
        float4 bv = ld4(&br[col[j]]);
        dot = fmaf(bv.x, mvv[j].x, dot); dot = fmaf(bv.y, mvv[j].y, dot);
        dot = fmaf(bv.z, mvv[j].z, dot); dot = fmaf(bv.w, mvv[j].w, dot);
        bns = fmaf(bv.x, bv.x, bns); bns = fmaf(bv.y, bv.y, bns);
        bns = fmaf(bv.z, bv.z, bns); bns = fmaf(bv.w, bv.w, bns);
    }
    dot = wave_red(dot);
    bns = wave_red(bns);
    if (lane == 0) {
        float sim = -1.0f;
        if (mask[n]) sim = (dot * inv) / fmaxf(sqrtf(bns), 1e-12f);
        unsigned int fb = __float_as_uint(sim);
        unsigned int mono = (fb & 0x80000000u) ? ~fb : (fb | 0x80000000u);
        // ~n in low bits => ties resolve to smallest index (jnp.argmax)
        unsigned long long key = ((unsigned long long)mono << 32) | (unsigned int)(~n);
        atomicMax((unsigned long long*)&ws[OFF_KEY], key);
    }
}

// ---------------- K4: pass B — decode winner, project, write out --------------
// 512 blocks x 256; 8 rows/wave, same full-depth load burst; per-pair stores
// issue as a dependency-free 8-store burst right after proj resolves.
__global__ __launch_bounds__(256, 2) void k_passB(const float* __restrict__ x,
                                                  const float* __restrict__ buf,
                                                  const float* __restrict__ facil,
                                                  const float* __restrict__ lkb,
                                                  const float* __restrict__ lkd,
                                                  const float* __restrict__ ws,
                                                  float* __restrict__ out) {
    __shared__ float s_v[D];
    __shared__ float s_red[4];
    __shared__ float s_sc[3];   // dampe, coef, valid
    const int tid = threadIdx.x, wave = tid >> 6, lane = tid & 63;

    const unsigned long long key = *(const unsigned long long*)&ws[OFF_KEY];
    const int idx = (int)(~(unsigned int)(key & 0xFFFFFFFFull));
    const unsigned int mono = (unsigned int)(key >> 32);
    const unsigned int fb = (mono & 0x80000000u) ? (mono ^ 0x80000000u) : ~mono;
    const float sim = __uint_as_float(fb);

    float4 vt = ld4(&buf[(size_t)idx * D + 4 * tid]);
    float bns = 0.f;
    if (!isfinite(vt.x) || !isfinite(vt.y) || !isfinite(vt.z) || !isfinite(vt.w))
        bns = __uint_as_float(0x7FC00000u);   // NaN poison -> valid=0
    bns += vt.x * vt.x + vt.y * vt.y + vt.z * vt.z + vt.w * vt.w;
    bns = wave_red(bns);
    if (lane == 0) s_red[wave] = bns;
    __syncthreads();
    if (tid == 0) {
        float t = s_red[0] + s_red[1] + s_red[2] + s_red[3];
        int valid = (t >= 1e-12f) ? 1 : 0;    // NaN compares false
        float sim_val = fminf(fmaxf(sim, 0.0f), 1.0f);
        float fl = facil[idx] * ((sim_val > 0.88f) ? 2.0f : 1.0f);
        float mod = (fl - 1.0f) * sim_val;
        float kb = fminf(fmaxf(__expf(lkb[0]), 0.01f), 4.0f);
        float kd = fminf(fmaxf(__expf(lkd[0]), 0.01f), 0.9f);
        float boost = 1.0f + kb * mod;
        float damp = fmaxf(0.01f, 1.0f - kd * mod);
        s_sc[0] = valid ? damp : 1.0f;
        s_sc[1] = valid ? (boost - damp) : 0.0f;
        s_sc[2] = (float)valid;
    }
    __syncthreads();
    const float dampe = s_sc[0], coef = s_sc[1];
    if (s_sc[2] == 0.0f) vt = make_float4(0.f, 0.f, 0.f, 0.f);
    *(float4*)&s_v[4 * tid] = vt;
    __syncthreads();

    int col[4];
    float4 vv[4];
    #pragma unroll
    for (int j = 0; j < 4; ++j) {
        col[j] = 4 * lane + 256 * j;
        vv[j] = *(const float4*)&s_v[col[j]];
    }

#define COMPPAIR_B(rr, XA, XB) do {                                            \
    const float gA = ws[OFF_GATE + (rr)], gB = ws[OFF_GATE + (rr) + 1];        \
    float4 yA[4], yB[4];                                                       \
    float projA = 0.f, projB = 0.f;                                            \
    _Pragma("unroll")                                                          \
    for (int j = 0; j < 4; ++j) {                                              \
        yA[j] = gelu4(XA[j]);                                                  \
        yA[j].x *= gA; yA[j].y *= gA; yA[j].z *= gA; yA[j].w *= gA;            \
        yB[j] = gelu4(XB[j]);                                                  \
        yB[j].x *= gB; yB[j].y *= gB; yB[j].z *= gB; yB[j].w *= gB;            \
        projA = fmaf(yA[j].x, vv[j].x, projA); projA = fmaf(yA[j].y, vv[j].y, projA); \
        projA = fmaf(yA[j].z, vv[j].z, projA); projA = fmaf(yA[j].w, vv[j].w, projA); \
        projB = fmaf(yB[j].x, vv[j].x, projB); projB = fmaf(yB[j].y, vv[j].y, projB); \
        projB = fmaf(yB[j].z, vv[j].z, projB); projB = fmaf(yB[j].w, vv[j].w, projB); \
    }                                                                          \
    projA = wave_red(projA);                                                   \
    projB = wave_red(projB);                                                   \
    const float pcA = projA * coef, pcB = projB * coef;                        \
    float* oA = out + (size_t)(rr) * D;                                        \
    float* oB = oA + D;                                                        \
    _Pragma("unroll")                                                          \
    for (int j = 0; j < 4; ++j) {                                              \
        float4 o;                                                              \
        o.x = fmaf(yA[j].x, dampe, pcA * vv[j].x);                             \
        o.y = fmaf(yA[j].y, dampe, pcA * vv[j].y);                             \
        o.z = fmaf(yA[j].z, dampe, pcA * vv[j].z);                             \
        o.w = fmaf(yA[j].w, dampe, pcA * vv[j].w);                             \
        st4_nt(&oA[col[j]], o);                                                \
        o.x = fmaf(yB[j].x, dampe, pcB * vv[j].x);                             \
        o.y = fmaf(yB[j].y, dampe, pcB * vv[j].y);                             \
        o.z = fmaf(yB[j].z, dampe, pcB * vv[j].z);                             \
        o.w = fmaf(yB[j].w, dampe, pcB * vv[j].w);                             \
        st4_nt(&oB[col[j]], o);                                                \
    }                                                                          \
} while (0)

    const int r0 = (blockIdx.x * 4 + wave) * 8;   // 8 rows/wave, 4 pairs
    float4 xA0[4], xB0[4], xA1[4], xB1[4], xA2[4], xB2[4], xA3[4], xB3[4];

    // full-depth load burst: 32 loads in flight before any compute
    LOADPAIR(r0 + 0, xA0, xB0);
    LOADPAIR(r0 + 2, xA1, xB1);
    LOADPAIR(r0 + 4, xA2, xB2);
    LOADPAIR(r0 + 6, xA3, xB3);
    COMPPAIR_B(r0 + 0, xA0, xB0);
    COMPPAIR_B(r0 + 2, xA1, xB1);
    COMPPAIR_B(r0 + 4, xA2, xB2);
    COMPPAIR_B(r0 + 6, xA3, xB3);
#undef COMPPAIR_B
}

extern "C" void kernel_launch(void* const* d_in, const int* in_sizes, int n_in,
                              void* d_out, int out_size, void* d_ws, size_t ws_size,
                              hipStream_t stream) {
    const float* x      = (const float*)d_in[0];
    const float* lti    = (const float*)d_in[1];
    const float* lto    = (const float*)d_in[2];
    const float* lai    = (const float*)d_in[3];
    const float* lao    = (const float*)d_in[4];
    const float* lkb    = (const float*)d_in[5];
    const float* lkd    = (const float*)d_in[6];
    const float* ema_x  = (const float*)d_in[7];
    const float* ema_x2 = (const float*)d_in[8];
    const float* ema_y  = (const float*)d_in[9];
    const float* ema_y2 = (const float*)d_in[10];
    const float* buf    = (const float*)d_in[11];
    const float* facil  = (const float*)d_in[12];
    const unsigned char* mask = (const unsigned char*)d_in[13];
    float* ws  = (float*)d_ws;
    float* out = (float*)d_out;

    (void)hipMemsetAsync(d_ws, 0, ZERO_BYTES, stream);
    hipLaunchKernelGGL(k_passA, dim3(NBLKA), dim3(256), 0, stream,
                       x, ema_x, ema_x2, ema_y, ema_y2, lti, lto, lai, lao, ws);
    hipLaunchKernelGGL(k_mean,  dim3(NSLOT / 16), dim3(256), 0, stream, ws);
    hipLaunchKernelGGL(k_sims,  dim3(128), dim3(256), 0, stream, buf, mask, ws);
    hipLaunchKernelGGL(k_passB, dim3(NBLKA), dim3(256), 0, stream,
                       x, buf, facil, lkb, lkd, ws, out);
}

// Round 9
// 176.095 us; speedup vs baseline: 1.7288x; 1.0056x over previous
//
#include <hip/hip_runtime.h>
#include <math.h>

#define D 1024
#define NROWS 16384
#define NBUF 512
#define NBLKA 512    // passA/passB: 4 waves/block, 8 rows/wave, fenced load burst
#define NSLOT 512    // one PART slot per block -> plain stores, no atomics

// ws layout (float indices)
#define OFF_MEAN 0      // 1024 floats: column sums of y1
#define OFF_KEY  1024   // unsigned long long at byte 4096
#define OFF_GATE 2048   // 16384 floats
#define OFF_PART 20480  // NSLOT x 1024 floats (plain-stored partials)
#define ZERO_BYTES 4112 // MEAN + KEY only (PART fully overwritten)

// Compiler scheduling fence: loads issued above may NOT be sunk below.
// asm memory clobber pins memory ops; sched_barrier(0) pins the scheduler.
#define SCHED_FENCE() do {                                                     \
    asm volatile("" ::: "memory");                                             \
    __builtin_amdgcn_sched_barrier(0);                                         \
} while (0)

typedef float nfloat4 __attribute__((ext_vector_type(4)));

__device__ __forceinline__ float4 ld4(const float* p) { return *(const float4*)p; }
__device__ __forceinline__ void st4_nt(float* p, float4 v) {
    nfloat4 nv = { v.x, v.y, v.z, v.w };
    __builtin_nontemporal_store(nv, (nfloat4*)p);
}

__device__ __forceinline__ float wave_red(float v) {
    #pragma unroll
    for (int off = 32; off > 0; off >>= 1) v += __shfl_xor(v, off, 64);
    return v;
}

__device__ __forceinline__ float gelu_f(float x) {
    float x2 = x * x;
    float t1 = fmaf(0.044715f, x2, 1.0f);
    float u2 = (1.5957691216057308f * x) * t1;
    float e  = __expf(u2);
    float r  = __builtin_amdgcn_rcpf(e + 1.0f);
    return fmaf(-x, r, x);
}

__device__ __forceinline__ float4 gelu4(float4 x) {
    float4 y;
    y.x = gelu_f(x.x); y.y = gelu_f(x.y); y.z = gelu_f(x.z); y.w = gelu_f(x.w);
    return y;
}

// Load one row pair (rr, rr+1) into explicit register sets XA/XB.
#define LOADPAIR(rr, XA, XB) do {                                              \
    const float* _pA = x + (size_t)(rr) * D;                                   \
    const float* _pB = _pA + D;                                                \
    _Pragma("unroll")                                                          \
    for (int _j = 0; _j < 4; ++_j) {                                           \
        XA[_j] = ld4(&_pA[col[_j]]);                                           \
        XB[_j] = ld4(&_pB[col[_j]]);                                           \
    }                                                                          \
} while (0)

// ---------------- K1: pass A — gates + per-slot column partials ---------------
// 512 blocks x 256; 8 rows/wave. All 32 loads issue as one burst, then a
// SCHED_FENCE forbids the compiler from sinking them into the compute (r8:
// VGPR=84 proved it had collapsed the burst; burst depth is the BW lever per
// the r7 fillBuffer datum: 6.3 TB/s at 8% occupancy). Stats hoisted to regs.
__global__ __launch_bounds__(256, 2) void k_passA(const float* __restrict__ x,
                                                  const float* __restrict__ ema_x,
                                                  const float* __restrict__ ema_x2,
                                                  const float* __restrict__ ema_y,
                                                  const float* __restrict__ ema_y2,
                                                  const float* __restrict__ lti,
                                                  const float* __restrict__ lto,
                                                  const float* __restrict__ lai,
                                                  const float* __restrict__ lao,
                                                  float* __restrict__ ws) {
    __shared__ float s_stat[4096];   // ax | mx*ax | ay | my*ay
    __shared__ float s_acc[D];
    const int tid = threadIdx.x, wave = tid >> 6, lane = tid & 63;

    for (int i = tid; i < 1024; i += 256) {
        float mx = ema_x[i];
        float vx = fmaxf(ema_x2[i] - mx * mx, 0.0f);
        float ax = 1.0f / (sqrtf(vx) + 1e-5f);
        s_stat[i]        = ax;
        s_stat[1024 + i] = mx * ax;
        float my = ema_y[i];
        float vy = fmaxf(ema_y2[i] - my * my, 0.0f);
        float ay = 1.0f / (sqrtf(vy) + 1e-5f);
        s_stat[2048 + i] = ay;
        s_stat[3072 + i] = my * ay;
        s_acc[i] = 0.0f;
    }
    __syncthreads();

    const float tau_in = __expf(lti[0]), tau_out = __expf(lto[0]);
    const float a_in  = 1.0f / (1.0f + __expf(-lai[0]));
    const float a_out = 1.0f / (1.0f + __expf(-lao[0]));

    int col[4];
    #pragma unroll
    for (int j = 0; j < 4; ++j) col[j] = 4 * lane + 256 * j;

    // hoist stats to registers (pair-invariant): 16 float4
    float4 sa[4], sb[4], sc4[4], sd[4];
    #pragma unroll
    for (int j = 0; j < 4; ++j) {
        sa[j]  = *(const float4*)&s_stat[col[j]];
        sb[j]  = *(const float4*)&s_stat[1024 + col[j]];
        sc4[j] = *(const float4*)&s_stat[2048 + col[j]];
        sd[j]  = *(const float4*)&s_stat[3072 + col[j]];
    }

    float4 acc[4];
    #pragma unroll
    for (int j = 0; j < 4; ++j) acc[j] = make_float4(0.f, 0.f, 0.f, 0.f);

#define COMPPAIR_A(rr, XA, XB) do {                                            \
    float4 yA[4], yB[4];                                                       \
    float zinA = 0.f, zinB = 0.f, zoutA = 0.f, zoutB = 0.f;                    \
    _Pragma("unroll")                                                          \
    for (int j = 0; j < 4; ++j) {                                              \
        float d;                                                               \
        d = fmaf(XA[j].x, sa[j].x, -sb[j].x); zinA = fmaf(d, d, zinA);         \
        d = fmaf(XA[j].y, sa[j].y, -sb[j].y); zinA = fmaf(d, d, zinA);         \
        d = fmaf(XA[j].z, sa[j].z, -sb[j].z); zinA = fmaf(d, d, zinA);         \
        d = fmaf(XA[j].w, sa[j].w, -sb[j].w); zinA = fmaf(d, d, zinA);         \
        d = fmaf(XB[j].x, sa[j].x, -sb[j].x); zinB = fmaf(d, d, zinB);         \
        d = fmaf(XB[j].y, sa[j].y, -sb[j].y); zinB = fmaf(d, d, zinB);         \
        d = fmaf(XB[j].z, sa[j].z, -sb[j].z); zinB = fmaf(d, d, zinB);         \
        d = fmaf(XB[j].w, sa[j].w, -sb[j].w); zinB = fmaf(d, d, zinB);         \
        yA[j] = gelu4(XA[j]);                                                  \
        yB[j] = gelu4(XB[j]);                                                  \
        d = fmaf(yA[j].x, sc4[j].x, -sd[j].x); zoutA = fmaf(d, d, zoutA);      \
        d = fmaf(yA[j].y, sc4[j].y, -sd[j].y); zoutA = fmaf(d, d, zoutA);      \
        d = fmaf(yA[j].z, sc4[j].z, -sd[j].z); zoutA = fmaf(d, d, zoutA);      \
        d = fmaf(yA[j].w, sc4[j].w, -sd[j].w); zoutA = fmaf(d, d, zoutA);      \
        d = fmaf(yB[j].x, sc4[j].x, -sd[j].x); zoutB = fmaf(d, d, zoutB);      \
        d = fmaf(yB[j].y, sc4[j].y, -sd[j].y); zoutB = fmaf(d, d, zoutB);      \
        d = fmaf(yB[j].z, sc4[j].z, -sd[j].z); zoutB = fmaf(d, d, zoutB);      \
        d = fmaf(yB[j].w, sc4[j].w, -sd[j].w); zoutB = fmaf(d, d, zoutB);      \
    }                                                                          \
    zinA  = wave_red(zinA)  * (1.0f / D);                                      \
    zinB  = wave_red(zinB)  * (1.0f / D);                                      \
    zoutA = wave_red(zoutA) * (1.0f / D);                                      \
    zoutB = wave_red(zoutB) * (1.0f / D);                                      \
    float gA = ((1.0f - a_in)  + a_in  * __expf(-tau_in  * zinA)) *            \
               ((1.0f - a_out) + a_out * __expf(-tau_out * zoutA));            \
    float gB = ((1.0f - a_in)  + a_in  * __expf(-tau_in  * zinB)) *            \
               ((1.0f - a_out) + a_out * __expf(-tau_out * zoutB));            \
    if (lane == 0) { ws[OFF_GATE + (rr)] = gA; ws[OFF_GATE + (rr) + 1] = gB; } \
    _Pragma("unroll")                                                          \
    for (int j = 0; j < 4; ++j) {                                              \
        acc[j].x = fmaf(yA[j].x, gA, fmaf(yB[j].x, gB, acc[j].x));             \
        acc[j].y = fmaf(yA[j].y, gA, fmaf(yB[j].y, gB, acc[j].y));             \
        acc[j].z = fmaf(yA[j].z, gA, fmaf(yB[j].z, gB, acc[j].z));             \
        acc[j].w = fmaf(yA[j].w, gA, fmaf(yB[j].w, gB, acc[j].w));             \
    }                                                                          \
} while (0)

    const int r0 = (blockIdx.x * 4 + wave) * 8;   // 8 rows/wave, 4 pairs
    float4 xA0[4], xB0[4], xA1[4], xB1[4], xA2[4], xB2[4], xA3[4], xB3[4];

    // full-depth load burst: 32 loads issued, FENCED against sinking
    LOADPAIR(r0 + 0, xA0, xB0);
    LOADPAIR(r0 + 2, xA1, xB1);
    LOADPAIR(r0 + 4, xA2, xB2);
    LOADPAIR(r0 + 6, xA3, xB3);
    SCHED_FENCE();
    COMPPAIR_A(r0 + 0, xA0, xB0);
    COMPPAIR_A(r0 + 2, xA1, xB1);
    COMPPAIR_A(r0 + 4, xA2, xB2);
    COMPPAIR_A(r0 + 6, xA3, xB3);
#undef COMPPAIR_A

    #pragma unroll
    for (int j = 0; j < 4; ++j) {
        atomicAdd(&s_acc[col[j] + 0], acc[j].x);
        atomicAdd(&s_acc[col[j] + 1], acc[j].y);
        atomicAdd(&s_acc[col[j] + 2], acc[j].z);
        atomicAdd(&s_acc[col[j] + 3], acc[j].w);
    }
    __syncthreads();
    // unique PART slot per block -> plain store, no atomics, no pre-zero
    *(float4*)&ws[OFF_PART + (size_t)blockIdx.x * D + 4 * tid] = *(float4*)&s_acc[4 * tid];
}

// ---------------- K2: reduce 512 partial slots -> column sums -----------------
__global__ __launch_bounds__(256) void k_mean(float* __restrict__ ws) {
    const int tid = threadIdx.x;
    const float* P = &ws[OFF_PART + (size_t)blockIdx.x * 16 * D];
    float4 s = make_float4(0.f, 0.f, 0.f, 0.f);
    #pragma unroll
    for (int i = 0; i < 16; ++i) {
        float4 v = ld4(&P[(size_t)i * D + 4 * tid]);
        s.x += v.x; s.y += v.y; s.z += v.z; s.w += v.w;
    }
    atomicAdd(&ws[OFF_MEAN + 4 * tid + 0], s.x);
    atomicAdd(&ws[OFF_MEAN + 4 * tid + 1], s.y);
    atomicAdd(&ws[OFF_MEAN + 4 * tid + 2], s.z);
    atomicAdd(&ws[OFF_MEAN + 4 * tid + 3], s.w);
}

// ---------------- K3: sims over buf + argmax via atomicMax key ----------------
__global__ __launch_bounds__(256) void k_sims(const float* __restrict__ buf,
                                              const unsigned char* __restrict__ mask,
                                              float* __restrict__ ws) {
    __shared__ float s_red[4];
    __shared__ float s_inv;
    const int tid = threadIdx.x, wave = tid >> 6, lane = tid & 63;

    float4 mv = ld4(&ws[OFF_MEAN + 4 * tid]);
    float ns = mv.x * mv.x + mv.y * mv.y + mv.z * mv.z + mv.w * mv.w;
    ns = wave_red(ns);
    if (lane == 0) s_red[wave] = ns;
    __syncthreads();
    if (tid == 0) {
        float t = s_red[0] + s_red[1] + s_red[2] + s_red[3];
        s_inv = 1.0f / fmaxf(sqrtf(t), 1e-12f);
    }
    __syncthreads();
    const float inv = s_inv;

    int col[4];
    float4 mvv[4];
    #pragma unroll
    for (int j = 0; j < 4; ++j) {
        col[j] = 4 * lane + 256 * j;
        mvv[j] = ld4(&ws[OFF_MEAN + col[j]]);
    }
    const int n = blockIdx.x * 4 + wave;   // 128 blocks x 4 waves = 512 rows
    const float* br = buf + (size_t)n * D;
    float dot = 0.f, bns = 0.f;
    #pragma unroll
    for (int j = 0; j < 4; ++j) {
        float4 bv = ld4(&br[col[j]]);
        dot = fmaf(bv.x, mvv[j].x, dot); dot = fmaf(bv.y, mvv[j].y, dot);
        dot = fmaf(bv.z, mvv[j].z, dot); dot = fmaf(bv.w, mvv[j].w, dot);
        bns = fmaf(bv.x, bv.x, bns); bns = fmaf(bv.y, bv.y, bns);
        bns = fmaf(bv.z, bv.z, bns); bns = fmaf(bv.w, bv.w, bns);
    }
    dot = wave_red(dot);
    bns = wave_red(bns);
    if (lane == 0) {
        float sim = -1.0f;
        if (mask[n]) sim = (dot * inv) / fmaxf(sqrtf(bns), 1e-12f);
        unsigned int fb = __float_as_uint(sim);
        unsigned int mono = (fb & 0x80000000u) ? ~fb : (fb | 0x80000000u);
        // ~n in low bits => ties resolve to smallest index (jnp.argmax)
        unsigned long long key = ((unsigned long long)mono << 32) | (unsigned int)(~n);
        atomicMax((unsigned long long*)&ws[OFF_KEY], key);
    }
}

// ---------------- K4: pass B — decode winner, project, write out --------------
// 512 blocks x 256; 8 rows/wave, fenced load burst; gates prefetched as 2
// float4 into the burst region (was 2 dependent scalar loads per pair).
__global__ __launch_bounds__(256, 2) void k_passB(const float* __restrict__ x,
                                                  const float* __restrict__ buf,
                                                  const float* __restrict__ facil,
                                                  const float* __restrict__ lkb,
                                                  const float* __restrict__ lkd,
                                                  const float* __restrict__ ws,
                                                  float* __restrict__ out) {
    __shared__ float s_v[D];
    __shared__ float s_red[4];
    __shared__ float s_sc[3];   // dampe, coef, valid
    const int tid = threadIdx.x, wave = tid >> 6, lane = tid & 63;

    const unsigned long long key = *(const unsigned long long*)&ws[OFF_KEY];
    const int idx = (int)(~(unsigned int)(key & 0xFFFFFFFFull));
    const unsigned int mono = (unsigned int)(key >> 32);
    const unsigned int fb = (mono & 0x80000000u) ? (mono ^ 0x80000000u) : ~mono;
    const float sim = __uint_as_float(fb);

    float4 vt = ld4(&buf[(size_t)idx * D + 4 * tid]);
    float bns = 0.f;
    if (!isfinite(vt.x) || !isfinite(vt.y) || !isfinite(vt.z) || !isfinite(vt.w))
        bns = __uint_as_float(0x7FC00000u);   // NaN poison -> valid=0
    bns += vt.x * vt.x + vt.y * vt.y + vt.z * vt.z + vt.w * vt.w;
    bns = wave_red(bns);
    if (lane == 0) s_red[wave] = bns;
    __syncthreads();
    if (tid == 0) {
        float t = s_red[0] + s_red[1] + s_red[2] + s_red[3];
        int valid = (t >= 1e-12f) ? 1 : 0;    // NaN compares false
        float sim_val = fminf(fmaxf(sim, 0.0f), 1.0f);
        float fl = facil[idx] * ((sim_val > 0.88f) ? 2.0f : 1.0f);
        float mod = (fl - 1.0f) * sim_val;
        float kb = fminf(fmaxf(__expf(lkb[0]), 0.01f), 4.0f);
        float kd = fminf(fmaxf(__expf(lkd[0]), 0.01f), 0.9f);
        float boost = 1.0f + kb * mod;
        float damp = fmaxf(0.01f, 1.0f - kd * mod);
        s_sc[0] = valid ? damp : 1.0f;
        s_sc[1] = valid ? (boost - damp) : 0.0f;
        s_sc[2] = (float)valid;
    }
    __syncthreads();
    const float dampe = s_sc[0], coef = s_sc[1];
    if (s_sc[2] == 0.0f) vt = make_float4(0.f, 0.f, 0.f, 0.f);
    *(float4*)&s_v[4 * tid] = vt;
    __syncthreads();

    int col[4];
    float4 vv[4];
    #pragma unroll
    for (int j = 0; j < 4; ++j) {
        col[j] = 4 * lane + 256 * j;
        vv[j] = *(const float4*)&s_v[col[j]];
    }

#define COMPPAIR_B(rr, XA, XB, gA, gB) do {                                    \
    float4 yA[4], yB[4];                                                       \
    float projA = 0.f, projB = 0.f;                                            \
    _Pragma("unroll")                                                          \
    for (int j = 0; j < 4; ++j) {                                              \
        yA[j] = gelu4(XA[j]);                                                  \
        yA[j].x *= gA; yA[j].y *= gA; yA[j].z *= gA; yA[j].w *= gA;            \
        yB[j] = gelu4(XB[j]);                                                  \
        yB[j].x *= gB; yB[j].y *= gB; yB[j].z *= gB; yB[j].w *= gB;            \
        projA = fmaf(yA[j].x, vv[j].x, projA); projA = fmaf(yA[j].y, vv[j].y, projA); \
        projA = fmaf(yA[j].z, vv[j].z, projA); projA = fmaf(yA[j].w, vv[j].w, projA); \
        projB = fmaf(yB[j].x, vv[j].x, projB); projB = fmaf(yB[j].y, vv[j].y, projB); \
        projB = fmaf(yB[j].z, vv[j].z, projB); projB = fmaf(yB[j].w, vv[j].w, projB); \
    }                                                                          \
    projA = wave_red(projA);                                                   \
    projB = wave_red(projB);                                                   \
    const float pcA = projA * coef, pcB = projB * coef;                        \
    float* oA = out + (size_t)(rr) * D;                                        \
    float* oB = oA + D;                                                        \
    _Pragma("unroll")                                                          \
    for (int j = 0; j < 4; ++j) {                                              \
        float4 o;                                                              \
        o.x = fmaf(yA[j].x, dampe, pcA * vv[j].x);                             \
        o.y = fmaf(yA[j].y, dampe, pcA * vv[j].y);                             \
        o.z = fmaf(yA[j].z, dampe, pcA * vv[j].z);                             \
        o.w = fmaf(yA[j].w, dampe, pcA * vv[j].w);                             \
        st4_nt(&oA[col[j]], o);                                                \
        o.x = fmaf(yB[j].x, dampe, pcB * vv[j].x);                             \
        o.y = fmaf(yB[j].y, dampe, pcB * vv[j].y);                             \
        o.z = fmaf(yB[j].z, dampe, pcB * vv[j].z);                             \
        o.w = fmaf(yB[j].w, dampe, pcB * vv[j].w);                             \
        st4_nt(&oB[col[j]], o);                                                \
    }                                                                          \
} while (0)

    const int r0 = (blockIdx.x * 4 + wave) * 8;   // 8 rows/wave, 4 pairs
    float4 xA0[4], xB0[4], xA1[4], xB1[4], xA2[4], xB2[4], xA3[4], xB3[4];

    // full-depth burst: 32 x-loads + 2 gate-float4, FENCED against sinking
    LOADPAIR(r0 + 0, xA0, xB0);
    LOADPAIR(r0 + 2, xA1, xB1);
    LOADPAIR(r0 + 4, xA2, xB2);
    LOADPAIR(r0 + 6, xA3, xB3);
    float4 g03 = ld4(&ws[OFF_GATE + r0]);
    float4 g47 = ld4(&ws[OFF_GATE + r0 + 4]);
    SCHED_FENCE();
    COMPPAIR_B(r0 + 0, xA0, xB0, g03.x, g03.y);
    COMPPAIR_B(r0 + 2, xA1, xB1, g03.z, g03.w);
    COMPPAIR_B(r0 + 4, xA2, xB2, g47.x, g47.y);
    COMPPAIR_B(r0 + 6, xA3, xB3, g47.z, g47.w);
#undef COMPPAIR_B
}

extern "C" void kernel_launch(void* const* d_in, const int* in_sizes, int n_in,
                              void* d_out, int out_size, void* d_ws, size_t ws_size,
                              hipStream_t stream) {
    const float* x      = (const float*)d_in[0];
    const float* lti    = (const float*)d_in[1];
    const float* lto    = (const float*)d_in[2];
    const float* lai    = (const float*)d_in[3];
    const float* lao    = (const float*)d_in[4];
    const float* lkb    = (const float*)d_in[5];
    const float* lkd    = (const float*)d_in[6];
    const float* ema_x  = (const float*)d_in[7];
    const float* ema_x2 = (const float*)d_in[8];
    const float* ema_y  = (const float*)d_in[9];
    const float* ema_y2 = (const float*)d_in[10];
    const float* buf    = (const float*)d_in[11];
    const float* facil  = (const float*)d_in[12];
    const unsigned char* mask = (const unsigned char*)d_in[13];
    float* ws  = (float*)d_ws;
    float* out = (float*)d_out;

    (void)hipMemsetAsync(d_ws, 0, ZERO_BYTES, stream);
    hipLaunchKernelGGL(k_passA, dim3(NBLKA), dim3(256), 0, stream,
                       x, ema_x, ema_x2, ema_y, ema_y2, lti, lto, lai, lao, ws);
    hipLaunchKernelGGL(k_mean,  dim3(NSLOT / 16), dim3(256), 0, stream, ws);
    hipLaunchKernelGGL(k_sims,  dim3(128), dim3(256), 0, stream, buf, mask, ws);
    hipLaunchKernelGGL(k_passB, dim3(NBLKA), dim3(256), 0, stream,
                       x, buf, facil, lkb, lkd, ws, out);
}